// Round 10
// baseline (319.550 us; speedup 1.0000x reference)
//
#include <hip/hip_runtime.h>
#include <stdint.h>

#define SEQ   2048
#define DIM   1024
#define BATCH 4

typedef _Float16 f16;
typedef __attribute__((ext_vector_type(8))) _Float16 f16x8;
typedef __attribute__((ext_vector_type(4))) _Float16 f16x4;
typedef __attribute__((ext_vector_type(4))) float   f32x4;

typedef void __attribute__((address_space(1))) vg_t;
typedef void __attribute__((address_space(3))) vl_t;

__device__ __forceinline__ void gld16(const void* g, void* l) {
  // async global->LDS, 16B per lane; LDS dest = wave-uniform base + lane*16
  __builtin_amdgcn_global_load_lds((vg_t*)g, (vl_t*)l, 16, 0, 0);
}

// ---------------------------------------------------------------------------
// Fused fp32->fp16 convert of x, Wq, Wk, Wv in ONE dispatch.
// ---------------------------------------------------------------------------
__global__ __launch_bounds__(256) void cvt_all(const float* __restrict__ x,
                                               const float* __restrict__ wq,
                                               const float* __restrict__ wk,
                                               const float* __restrict__ wv,
                                               f16* __restrict__ xb,
                                               f16* __restrict__ wh) {
  const int bx = blockIdx.x;
  const float* in; f16* out; int base;
  if (bx < 8192)       { in = x;  out = xb;             base = bx; }
  else if (bx < 9216)  { in = wq; out = wh;             base = bx - 8192; }
  else if (bx < 10240) { in = wk; out = wh + (1 << 20); base = bx - 9216; }
  else                 { in = wv; out = wh + (2 << 20); base = bx - 10240; }
  const long i = ((long)base * 256 + threadIdx.x) * 4;
  float4 v = *(const float4*)(in + i);
  f16x4 o = { (f16)v.x, (f16)v.y, (f16)v.z, (f16)v.w };
  *(f16x4*)(out + i) = o;
}

// ---------------------------------------------------------------------------
// QKV NT GEMM (proven 67.2us config, CONTROL -- unchanged from r9).
// ---------------------------------------------------------------------------
template <int MODE, int CAUSAL, int BK>
__global__ __launch_bounds__(256) void gemm_bt(const f16* __restrict__ A, int lda, long aOffZ,
                                               const f16* __restrict__ B, int ldb, long bOffZ,
                                               void* __restrict__ Cv, int ldc, long cOffZ,
                                               int K) {
  constexpr int CH  = BK / 8;
  constexpr int RPL = 64 / CH;
  constexpr int NL  = 32 / RPL;
  __shared__ __align__(16) f16 lA[128 * BK];
  __shared__ __align__(16) f16 lB[128 * BK];

  const int tid  = threadIdx.x;
  const int wave = tid >> 6;
  const int lane = tid & 63;

  const int m0 = blockIdx.x * 128;
  const int n0 = blockIdx.y * 128;
  const int z  = blockIdx.z;
  const int Keff = K;

  const f16* Ab = A + (long)z * aOffZ + (long)m0 * lda;
  const f16* Bb = B + (long)z * bOffZ + (long)n0 * ldb;

  const int wm = (wave & 1) * 64;
  const int wn = (wave >> 1) * 64;

  f32x4 acc[4][4] = {};

  const int srow = lane / CH;
  const int sj   = lane % CH;
  const int fr   = lane & 15;
  const int fq   = lane >> 4;

  for (int kt = 0; kt < Keff; kt += BK) {
    __syncthreads();
#pragma unroll
    for (int j = 0; j < NL; ++j) {
      const int rgrp = j * 4 + wave;
      const int row  = rgrp * RPL + srow;
      const int gch  = sj ^ (row & (CH - 1));
      gld16(Ab + (long)row * lda + kt + gch * 8, (void*)(lA + rgrp * 512 + lane * 8));
      gld16(Bb + (long)row * ldb + kt + gch * 8, (void*)(lB + rgrp * 512 + lane * 8));
    }
    __syncthreads();

#pragma unroll
    for (int kk = 0; kk < BK; kk += 32) {
      f16x8 af[4], bf[4];
#pragma unroll
      for (int i = 0; i < 4; ++i) {
        const int arow = wm + i * 16 + fr;
        const int ach  = (kk / 8 + fq) ^ (arow & (CH - 1));
        af[i] = *(const f16x8*)(lA + arow * BK + ach * 8);
        const int brow = wn + i * 16 + fr;
        const int bch  = (kk / 8 + fq) ^ (brow & (CH - 1));
        bf[i] = *(const f16x8*)(lB + brow * BK + bch * 8);
      }
#pragma unroll
      for (int mi = 0; mi < 4; ++mi)
#pragma unroll
        for (int ni = 0; ni < 4; ++ni)
          acc[mi][ni] = __builtin_amdgcn_mfma_f32_16x16x32_f16(af[mi], bf[ni], acc[mi][ni], 0, 0, 0);
    }
  }

  // Epilogue. C/D layout: col = lane&15, row = (lane>>4)*4 + reg
#pragma unroll
  for (int mi = 0; mi < 4; ++mi) {
    const int row = m0 + wm + mi * 16 + fq * 4;
#pragma unroll
    for (int ni = 0; ni < 4; ++ni) {
      const int col = n0 + wn + ni * 16 + fr;
      if constexpr (MODE == 3) {  // fused QKV routing (wave-uniform regions)
        f16* Qh  = (f16*)Cv;
        f16* Kh  = Qh + (size_t)8 * 1024 * 1024;
        f16* VTb = Kh + (size_t)8 * 1024 * 1024;
        if (col < 1024) {
#pragma unroll
          for (int r = 0; r < 4; ++r) Qh[(long)(row + r) * DIM + col] = (f16)acc[mi][ni][r];
        } else if (col < 2048) {
#pragma unroll
          for (int r = 0; r < 4; ++r) Kh[(long)(row + r) * DIM + (col - 1024)] = (f16)acc[mi][ni][r];
        } else {
          f16x4 o = { (f16)acc[mi][ni][0], (f16)acc[mi][ni][1],
                      (f16)acc[mi][ni][2], (f16)acc[mi][ni][3] };
          *(f16x4*)(VTb + (long)(col - 2048) * (BATCH * SEQ) + row) = o;
        }
      } else {
        float* C = (float*)Cv + (long)z * cOffZ;
#pragma unroll
        for (int r = 0; r < 4; ++r) C[(long)(row + r) * ldc + col] = acc[mi][ni][r];
      }
    }
  }
}

// ---------------------------------------------------------------------------
// 64x128 tile GEMM (scores MODE 1 / PV MODE 0), structure as r9.
// REP (measurement): the WHOLE body, including the epilogue store, runs REP
// times. Stores are side effects -> no DCE possible; writes are byte-identical
// -> bit-exact output. Profiled duration of this dispatch = REP x true
// duration, so REP=2 surfaces the kernel in top-5 iff true > ~34us, and the
// timed-total delta = (REP-1) x true timed duration. Diagnostic only.
// ---------------------------------------------------------------------------
template <int MODE, int REP>
__global__ __launch_bounds__(256) void gemm64(const f16* __restrict__ A, int lda, long aOffZ,
                                              const f16* __restrict__ B, int ldb, long bOffZ,
                                              void* __restrict__ Cv, int ldc, long cOffZ,
                                              int K) {
  constexpr int BK = 64;
  __shared__ __align__(16) f16 lA[64 * BK];    //  8 KB
  __shared__ __align__(16) f16 lB[128 * BK];   // 16 KB

  const int tid  = threadIdx.x;
  const int wave = tid >> 6;
  const int lane = tid & 63;
  const int srow = lane >> 3;
  const int sj   = lane & 7;
  const int fr   = lane & 15;
  const int fq   = lane >> 4;
  const int wm   = (wave & 1) * 32;
  const int wn   = (wave >> 1) * 64;

  int m0, n0, z, Keff;
  if (MODE == 1) {                     // scores: compact causal decode
    const int b = blockIdx.x;
    z = b / 272;
    int rem = b - z * 272;
    int mt = 0;
    while (true) { const int c = (mt >> 1) + 1; if (rem < c) break; rem -= c; ++mt; }
    m0 = mt * 64; n0 = rem * 128; Keff = K;
  } else {                             // PV: balanced decode, 1024 blocks
    const int id   = blockIdx.x;
    const int item = (id < 512) ? id : 1535 - id;
    const int mt   = 31 - (item >> 5);
    const int j    = item & 31;
    m0 = mt * 64; n0 = (j & 7) * 128; z = j >> 3; Keff = m0 + 64;
  }

  const f16* Ab = A + (long)z * aOffZ + (long)m0 * lda;
  const f16* Bb = B + (long)z * bOffZ + (long)n0 * ldb;

#pragma unroll 1
  for (int rep = 0; rep < REP; ++rep) {
    f32x4 acc[2][4] = {};

    for (int kt = 0; kt < Keff; kt += BK) {
      __syncthreads();
#pragma unroll
      for (int j = 0; j < 2; ++j) {      // A: 64 rows = 8 rgrps
        const int rgrp = j * 4 + wave;
        const int row  = rgrp * 8 + srow;
        const int gch  = sj ^ (row & 7);
        gld16(Ab + (long)row * lda + kt + gch * 8, (void*)(lA + rgrp * 512 + lane * 8));
      }
#pragma unroll
      for (int j = 0; j < 4; ++j) {      // B: 128 rows = 16 rgrps
        const int rgrp = j * 4 + wave;
        const int row  = rgrp * 8 + srow;
        const int gch  = sj ^ (row & 7);
        gld16(Bb + (long)row * ldb + kt + gch * 8, (void*)(lB + rgrp * 512 + lane * 8));
      }
      __syncthreads();

#pragma unroll
      for (int kk = 0; kk < BK; kk += 32) {
        f16x8 af[2], bf[4];
#pragma unroll
        for (int i = 0; i < 2; ++i) {
          const int arow = wm + i * 16 + fr;
          const int ach  = (kk / 8 + fq) ^ (arow & 7);
          af[i] = *(const f16x8*)(lA + arow * BK + ach * 8);
        }
#pragma unroll
        for (int i = 0; i < 4; ++i) {
          const int brow = wn + i * 16 + fr;
          const int bch  = (kk / 8 + fq) ^ (brow & 7);
          bf[i] = *(const f16x8*)(lB + brow * BK + bch * 8);
        }
#pragma unroll
        for (int mi = 0; mi < 2; ++mi)
#pragma unroll
          for (int ni = 0; ni < 4; ++ni)
            acc[mi][ni] = __builtin_amdgcn_mfma_f32_16x16x32_f16(af[mi], bf[ni], acc[mi][ni], 0, 0, 0);
      }
    }

    // Epilogue (inside rep loop: byte-identical rewrite, keeps all work live).
#pragma unroll
    for (int mi = 0; mi < 2; ++mi) {
      const int row = m0 + wm + mi * 16 + fq * 4;
#pragma unroll
      for (int ni = 0; ni < 4; ++ni) {
        const int col = n0 + wn + ni * 16 + fr;
        if constexpr (MODE == 1) {
          f16* C = (f16*)Cv + (long)z * cOffZ;
#pragma unroll
          for (int r = 0; r < 4; ++r) C[(long)(row + r) * ldc + col] = (f16)acc[mi][ni][r];
        } else {
          float* C = (float*)Cv + (long)z * cOffZ;
#pragma unroll
          for (int r = 0; r < 4; ++r) C[(long)(row + r) * ldc + col] = acc[mi][ni][r];
        }
      }
    }
  }
}

// ---------------------------------------------------------------------------
// Causal softmax, in-place. SREP (measurement): the compute phase (load, max-
// reduce, exp, sum-reduce -- incl. LDS reductions and barriers) runs SREP
// times; each rep's s is kept live via asm (no CSE/DCE); the WRITE happens
// once, using the last rep (in-place kernel -> must not write between reps).
// Output bit-exact. Profiled duration ~ SREP x compute + 1 x write.
// ---------------------------------------------------------------------------
template <int SREP>
__global__ __launch_bounds__(256) void softmax_causal(f16* S) {
  const int q = blockIdx.x, b = blockIdx.y;
  f16* row = S + ((long)b * SEQ + q) * SEQ;
  const int tid = threadIdx.x;
  const int lane = tid & 63, wave = tid >> 6;
  const int nvalid = q + 1;
  const int kneed  = ((q >> 6) + 1) << 6;  // 64-aligned: PV tile K-limit

  __shared__ float redm[4], reds[4];
  float v[8];
  float s = 1.f;

#pragma unroll 1
  for (int rep = 0; rep < SREP; ++rep) {
    f16x8 vv = {};
    if (tid * 8 < nvalid) vv = *(const f16x8*)(row + tid * 8);
    float m = -3.0e38f;
#pragma unroll
    for (int i = 0; i < 8; ++i) {
      const int k = tid * 8 + i;
      v[i] = (k < nvalid) ? (float)vv[i] * 0.03125f : -3.0e38f;
      m = fmaxf(m, v[i]);
    }
#pragma unroll
    for (int off = 32; off; off >>= 1) m = fmaxf(m, __shfl_xor(m, off));
    if (lane == 0) redm[wave] = m;
    __syncthreads();
    m = fmaxf(fmaxf(redm[0], redm[1]), fmaxf(redm[2], redm[3]));

    float sr = 0.f;
#pragma unroll
    for (int i = 0; i < 8; ++i) {
      const float p = (v[i] > -1.0e37f) ? __expf(v[i] - m) : 0.f;
      v[i] = p;
      sr += p;
    }
#pragma unroll
    for (int off = 32; off; off >>= 1) sr += __shfl_xor(sr, off);
    if (lane == 0) reds[wave] = sr;
    __syncthreads();
    sr = reds[0] + reds[1] + reds[2] + reds[3];
    asm volatile("" : : "v"(sr));   // keep every rep's chain live (rule #17)
    s = sr;
    __syncthreads();                // protect redm/reds before next rep
  }

  const float inv = 1.f / s;
  f16x8 o;
#pragma unroll
  for (int i = 0; i < 8; ++i) o[i] = (f16)(v[i] * inv);
  if (tid * 8 < kneed) *(f16x8*)(row + tid * 8) = o;
}

// ---------------------------------------------------------------------------
extern "C" void kernel_launch(void* const* d_in, const int* in_sizes, int n_in,
                              void* d_out, int out_size, void* d_ws, size_t ws_size,
                              hipStream_t stream) {
  const float* x  = (const float*)d_in[0];
  const float* Wq = (const float*)d_in[1];
  const float* Wk = (const float*)d_in[2];
  const float* Wv = (const float*)d_in[3];
  float* out = (float*)d_out;

  // ws layout (f16 elems): xb 8M | Wh 3M | Qh 8M | Kh 8M | VT 8M ([1024][8192]) |
  //                        Sc 16M f16 scores->probs in place (4 x 2048 x 2048)
  if (ws_size < (size_t)51 * 1024 * 1024 * 2) return;

  f16* xb = (f16*)d_ws;
  f16* Wh = xb + (size_t)8 * 1024 * 1024;
  f16* Qh = Wh + (size_t)3 * 1024 * 1024;
  f16* Kh = Qh + (size_t)8 * 1024 * 1024;
  f16* VT = Kh + (size_t)8 * 1024 * 1024;
  f16* Sc = VT + (size_t)8 * 1024 * 1024;

  const long QOFF = (long)SEQ * DIM;  // per-batch Q/K offset
  const long SOFF = (long)SEQ * SEQ;  // per-batch score offset (f16 elems)

  cvt_all<<<11264, 256, 0, stream>>>(x, Wq, Wk, Wv, xb, Wh);

  // Fused QKV (CONTROL, unchanged): 128x128/BK=64, 6 blocks/CU.
  gemm_bt<3, 0, 64><<<dim3(64, 24, 1), 256, 0, stream>>>(xb, DIM, 0, Wh, DIM, 0, Qh, 0, 0, DIM);

  // scores, AMPLIFIED x2 (measurement round): true dur = profiled/2; timed
  // cost = +1x true. Bit-exact output.
  gemm64<1, 2><<<1088, 256, 0, stream>>>(Qh, DIM, QOFF, Kh, DIM, QOFF,
                                         Sc, SEQ, SOFF, DIM);

  // softmax, compute AMPLIFIED x4, single write. Bit-exact.
  softmax_causal<4><<<dim3(SEQ, BATCH), 256, 0, stream>>>(Sc);

  // PV, AMPLIFIED x2. Bit-exact.
  gemm64<0, 2><<<1024, 256, 0, stream>>>(Sc, SEQ, SOFF, VT, BATCH * SEQ, SEQ,
                                         out, DIM, (long)SEQ * DIM, SEQ);
}